// Round 5
// baseline (843.079 us; speedup 1.0000x reference)
//
#include <hip/hip_runtime.h>

__device__ __forceinline__ float sigmoidf_(float x){ return 1.f/(1.f+__expf(-x)); }

// ---------- CSR build (proven in R5) ----------
__global__ void hist_kernel(const int* __restrict__ dst, int* __restrict__ cnt, int E){
  int e = blockIdx.x*blockDim.x + threadIdx.x;
  if (e < E) atomicAdd(&cnt[dst[e]], 1);
}

// cnt and wptr may ALIAS: cnt[i] read before wptr[i] written (same thread).
__global__ __launch_bounds__(1024) void scan_kernel(const int* __restrict__ cnt,
                                                    int* __restrict__ off,
                                                    int* __restrict__ wptr, int N){
  __shared__ int part[1024];
  const int t = threadIdx.x;
  const int chunk = (N + 1023) / 1024;
  const int lo = min(t*chunk, N), hi = min(lo+chunk, N);
  int s = 0;
  for (int i = lo; i < hi; i++) s += cnt[i];
  part[t] = s;
  __syncthreads();
  for (int o = 1; o < 1024; o <<= 1){
    int v = (t >= o) ? part[t-o] : 0;
    __syncthreads();
    part[t] += v;
    __syncthreads();
  }
  int run = part[t] - s;
  for (int i = lo; i < hi; i++){
    int c = cnt[i];
    off[i] = run; wptr[i] = run;
    run += c;
  }
  if (t == 1023) off[N] = part[1023];
}

__global__ void scatter_kernel(const int* __restrict__ dst, int* __restrict__ wptr,
                               int* __restrict__ csr, int E){
  int e = blockIdx.x*blockDim.x + threadIdx.x;
  if (e < E){
    int pos = atomicAdd(&wptr[dst[e]], 1);
    csr[pos] = e;
  }
}

// ---------- Edge phase v6a: dense per-edge GVP, lane = edge, CSR order ----------
// Writes per-edge outputs ecS[p][128], ecV[p][48] in CSR position order so the
// aggregation phase is a pure sequential stream. Weights have wave-uniform
// addresses (16 KB wes lives in L1/K$, reused by all chunks). es[32] is
// static-indexed in registers — per-edge cost is ~66 fmac wave-instrs, the
// structural floor.
__global__ __launch_bounds__(256) void edge_gvp_kernel(
    const float* __restrict__ edge_s, const float* __restrict__ edge_v,
    const int* __restrict__ csr,
    const float* __restrict__ wes, const float* __restrict__ bes,
    const float* __restrict__ wev, const float* __restrict__ bev,
    float* __restrict__ ecS, float* __restrict__ ecV, int E)
{
  __shared__ float shT[256*17];
  const int t = threadIdx.x;
  const int p0 = blockIdx.x*256;
  const int p  = p0 + t;
  const bool act = (p < E);

  int e = 0;
  if (act) e = csr[p];

  float es[32];
  if (act){
    #pragma unroll
    for (int k = 0; k < 32; k += 4){
      float4 u = *(const float4*)(edge_s + (size_t)e*32 + k);
      es[k]=u.x; es[k+1]=u.y; es[k+2]=u.z; es[k+3]=u.w;
    }
  } else {
    #pragma unroll
    for (int k = 0; k < 32; k++) es[k]=0.f;
  }
  float ev0=0.f, ev1=0.f, ev2=0.f;
  if (act){
    const float* pv = edge_v + (size_t)e*3;
    ev0 = pv[0]; ev1 = pv[1]; ev2 = pv[2];
  }

  float gate[16];

  // ---- scalar channels: 8 chunks of 16 ----
  for (int cb = 0; cb < 128; cb += 16){
    float acc[16];
    #pragma unroll
    for (int c = 0; c < 16; c++){
      float a = bes[cb+c];
      const float* wr = wes + (size_t)(cb+c)*32;
      #pragma unroll
      for (int k = 0; k < 32; k++) a += es[k]*wr[k];
      acc[c] = a * sigmoidf_(a);                       // silu
    }
    if (cb == 0){
      #pragma unroll
      for (int c = 0; c < 16; c++) gate[c] = sigmoidf_(acc[c]);
    }
    __syncthreads();   // WAR on shT from previous chunk
    #pragma unroll
    for (int c = 0; c < 16; c += 4)
      *(float4*)&shT[t*17 + c] = make_float4(acc[c],acc[c+1],acc[c+2],acc[c+3]);
    __syncthreads();
    #pragma unroll
    for (int q = 0; q < 4; q++){
      const int flat = q*256 + t;         // f4 index in 256x16 tile
      const int row  = flat >> 2;
      const int col  = (flat & 3)*4;
      if (p0 + row < E){
        const float* ps = &shT[row*17 + col];
        *(float4*)(ecS + (size_t)(p0+row)*128 + cb + col) =
          make_float4(ps[0], ps[1], ps[2], ps[3]);
      }
    }
  }

  // ---- vector channels: 3 chunks of 16 ----
  for (int vb = 0; vb < 48; vb += 16){
    float vo[16];
    #pragma unroll
    for (int cc = 0; cc < 16; cc++){
      const int c = vb + cc;
      vo[cc] = (bev[c] + wev[c*3]*ev0 + wev[c*3+1]*ev1 + wev[c*3+2]*ev2)
               * gate[c/3];
    }
    __syncthreads();
    #pragma unroll
    for (int c = 0; c < 16; c += 4)
      *(float4*)&shT[t*17 + c] = make_float4(vo[c],vo[c+1],vo[c+2],vo[c+3]);
    __syncthreads();
    #pragma unroll
    for (int q = 0; q < 4; q++){
      const int flat = q*256 + t;
      const int row  = flat >> 2;
      const int col  = (flat & 3)*4;
      if (p0 + row < E){
        const float* ps = &shT[row*17 + col];
        *(float4*)(ecV + (size_t)(p0+row)*48 + vb + col) =
          make_float4(ps[0], ps[1], ps[2], ps[3]);
      }
    }
  }
}

// ---------- Edge phase v6b: streaming segmented mean (rows already node-grouped) ----------
#define AGG_NB 16
__global__ __launch_bounds__(192) void agg_kernel(
    const float* __restrict__ ecS, const float* __restrict__ ecV,
    const int* __restrict__ off,
    float* __restrict__ aggS, float* __restrict__ aggV, int N)
{
  const int t = threadIdx.x;
  const int i0 = blockIdx.x*AGG_NB;
  const int i1 = min(i0 + AGG_NB, N);
  for (int i = i0; i < i1; i++){
    const int jb = off[i], je = off[i+1];
    const float rdn = 1.f / (float)max(je - jb, 1);
    if (t < 128){
      float a = 0.f;
      for (int j = jb; j < je; j++) a += ecS[(size_t)j*128 + t];
      aggS[(size_t)i*128 + t] = a * rdn;
    } else if (t < 176){
      const int c = t - 128;
      float a = 0.f;
      for (int j = jb; j < je; j++) a += ecV[(size_t)j*48 + c];
      aggV[(size_t)i*48 + c] = a * rdn;
    }
  }
}

// ---------- Fallback fused edge kernel (v5) — used only if workspace too small ----------
__global__ __launch_bounds__(128, 3) void edge_agg_kernel(
    const float* __restrict__ edge_s, const float* __restrict__ edge_v,
    const int* __restrict__ csr, const int* __restrict__ off,
    const float* __restrict__ wes, const float* __restrict__ bes,
    const float* __restrict__ wev, const float* __restrict__ bev,
    float* __restrict__ aggS, float* __restrict__ aggV, int N)
{
  const int t = threadIdx.x;
  float w[32];
  #pragma unroll
  for (int k = 0; k < 32; k += 4){
    float4 u = *(const float4*)(wes + t*32 + k);
    w[k]=u.x; w[k+1]=u.y; w[k+2]=u.z; w[k+3]=u.w;
  }
  const float bt = bes[t];
  float wv0=0.f, wv1=0.f, wv2=0.f, bv=0.f;
  if (t < 48){ wv0=wev[t*3]; wv1=wev[t*3+1]; wv2=wev[t*3+2]; bv=bev[t]; }

  const int i = blockIdx.x;
  if (i >= N) return;
  const int jb = __builtin_amdgcn_readfirstlane(off[i]);
  const int je = __builtin_amdgcn_readfirstlane(off[i+1]);

  float accS = 0.f, accV = 0.f;
  for (int j = jb; j < je; j++){
    const int e_ = csr[j];
    const float4* pr = (const float4*)(edge_s + (size_t)e_*32);
    float d0 = 0.f, d1 = 0.f;
    #pragma unroll
    for (int q = 0; q < 8; q += 2){
      float4 r0 = pr[q], r1 = pr[q+1];
      d0 += r0.x*w[4*q+0] + r0.y*w[4*q+1] + r0.z*w[4*q+2] + r0.w*w[4*q+3];
      d1 += r1.x*w[4*q+4] + r1.y*w[4*q+5] + r1.z*w[4*q+6] + r1.w*w[4*q+7];
    }
    const float acc = bt + d0 + d1;
    const float sil = acc * sigmoidf_(acc);
    accS += sil;
    if (t < 64){
      float ex=0.f, ey=0.f, ez=0.f;
      const float* pv = edge_v + (size_t)e_*3;
      ex = pv[0]; ey = pv[1]; ez = pv[2];
      const float g = __shfl(sil, t/3, 64);
      if (t < 48) accV += (bv + wv0*ex + wv1*ey + wv2*ez) * sigmoidf_(g);
    }
  }
  const float rdn = 1.f / (float)max(je - jb, 1);
  aggS[(size_t)i*128 + t] = accS * rdn;
  if (t < 48) aggV[(size_t)i*48 + t] = accV * rdn;
}

// ---------- Node phase v3: 64-node tiles, full-wave-uniform (scalar) weights ----------
#define NS_RS 68
#define NS_GS 17

__global__ __launch_bounds__(512, 4) void node_kernel(
    const float* __restrict__ node_s, const float* __restrict__ node_v,
    const float* __restrict__ ln_g, const float* __restrict__ ln_b,
    const float* __restrict__ wns, const float* __restrict__ bns,
    const float* __restrict__ wnv, const float* __restrict__ bnv,
    const float* __restrict__ wrs, const float* __restrict__ brs,
    const float* __restrict__ wrv, const float* __restrict__ brv,
    const float* __restrict__ aggS, const float* __restrict__ aggV,
    float* __restrict__ out_s, float* __restrict__ out_v, int N)
{
  __shared__ float shX[64*NS_RS];        // inS = sn + aggS   (current k-half)
  __shared__ float shS[64*NS_RS];        // sn                (current k-half)
  __shared__ float shP1[128], shP2[128]; // LN partial sums (2 k-halves)
  __shared__ float shGate[64*NS_GS];

  const int tid  = threadIdx.x;
  const int lane = tid & 63;
  const int wv   = __builtin_amdgcn_readfirstlane(tid >> 6);   // 0..7, SGPR
  const int i0   = blockIdx.x * 64;
  const int node = i0 + lane;

  // ---- LN stats: waves 0,1 each sum one k-half, lane = node ----
  if (wv < 2){
    float s1 = 0.f, s2 = 0.f;
    if (node < N){
      const float4* p = (const float4*)(node_s + (size_t)node*128 + wv*64);
      #pragma unroll
      for (int q = 0; q < 16; q++){
        const float4 v = p[q];
        s1 += (v.x+v.y)+(v.z+v.w);
        s2 += (v.x*v.x+v.y*v.y)+(v.z*v.z+v.w*v.w);
      }
    }
    shP1[wv*64+lane] = s1;
    shP2[wv*64+lane] = s2;
  }
  __syncthreads();

  float acc1[16], acc2[16];
  #pragma unroll
  for (int j = 0; j < 16; j++){ acc1[j]=0.f; acc2[j]=0.f; }
  const int cb = wv*16;

  for (int half = 0; half < 2; half++){
    const int kb = half*64;
    // ---- stage 64 nodes x 64 k: normalized (+agg) ----
    {
      const int n  = tid >> 3;           // 0..63
      const int kk = (tid & 7)*8;        // 0..56
      const int gn = i0 + n;
      const float s1 = shP1[n] + shP1[64+n];
      const float s2 = shP2[n] + shP2[64+n];
      const float m  = s1 * (1.f/128.f);
      const float r  = rsqrtf(s2*(1.f/128.f) - m*m + 1e-5f);
      float4 x0 = make_float4(0.f,0.f,0.f,0.f), x1 = x0, a0 = x0, a1v = x0;
      if (gn < N){
        const float4* ps = (const float4*)(node_s + (size_t)gn*128 + kb + kk);
        x0 = ps[0]; x1 = ps[1];
        const float4* pa = (const float4*)(aggS + (size_t)gn*128 + kb + kk);
        a0 = pa[0]; a1v = pa[1];
      }
      const float4 g0 = *(const float4*)(ln_g + kb + kk);
      const float4 g1 = *(const float4*)(ln_g + kb + kk + 4);
      const float4 b0 = *(const float4*)(ln_b + kb + kk);
      const float4 b1 = *(const float4*)(ln_b + kb + kk + 4);
      const float sn0 = (x0.x-m)*r*g0.x + b0.x;
      const float sn1 = (x0.y-m)*r*g0.y + b0.y;
      const float sn2 = (x0.z-m)*r*g0.z + b0.z;
      const float sn3 = (x0.w-m)*r*g0.w + b0.w;
      const float sn4 = (x1.x-m)*r*g1.x + b1.x;
      const float sn5 = (x1.y-m)*r*g1.y + b1.y;
      const float sn6 = (x1.z-m)*r*g1.z + b1.z;
      const float sn7 = (x1.w-m)*r*g1.w + b1.w;
      float* pS = &shS[n*NS_RS + kk];
      float* pX = &shX[n*NS_RS + kk];
      ((float4*)pS)[0] = make_float4(sn0,sn1,sn2,sn3);
      ((float4*)pS)[1] = make_float4(sn4,sn5,sn6,sn7);
      ((float4*)pX)[0] = make_float4(sn0+a0.x, sn1+a0.y, sn2+a0.z, sn3+a0.w);
      ((float4*)pX)[1] = make_float4(sn4+a1v.x, sn5+a1v.y, sn6+a1v.z, sn7+a1v.w);
    }
    __syncthreads();

    // ---- scalar GEMVs: wave-uniform weight rows, lane = node ----
    for (int kc = 0; kc < 64; kc += 8){
      const float4 xa = ((const float4*)&shX[lane*NS_RS + kc])[0];
      const float4 xb = ((const float4*)&shX[lane*NS_RS + kc])[1];
      const float4 sa = ((const float4*)&shS[lane*NS_RS + kc])[0];
      const float4 sb = ((const float4*)&shS[lane*NS_RS + kc])[1];
      #pragma unroll
      for (int j = 0; j < 16; j++){
        const float* w1 = wns + (size_t)(cb+j)*128 + kb + kc;
        const float* w2 = wrs + (size_t)(cb+j)*128 + kb + kc;
        const float4 u0 = ((const float4*)w1)[0], u1 = ((const float4*)w1)[1];
        const float4 y0 = ((const float4*)w2)[0], y1 = ((const float4*)w2)[1];
        acc1[j] += (xa.x*u0.x + xa.y*u0.y + xa.z*u0.z + xa.w*u0.w)
                 + (xb.x*u1.x + xb.y*u1.y + xb.z*u1.z + xb.w*u1.w);
        acc2[j] += (sa.x*y0.x + sa.y*y0.y + sa.z*y0.z + sa.w*y0.w)
                 + (sb.x*y1.x + sb.y*y1.y + sb.z*y1.z + sb.w*y1.w);
      }
    }
    __syncthreads();   // before restage (half=1) / before gate write (exit)
  }

  // ---- scalar epilogue: silu + gate + residual, contiguous float4 stores ----
  {
    float o[16];
    #pragma unroll
    for (int j = 0; j < 16; j++){
      const float aa = acc1[j] + bns[cb+j];
      const float so = aa * sigmoidf_(aa);          // silu
      if (wv == 0) shGate[lane*NS_GS + j] = sigmoidf_(so);
      o[j] = so + acc2[j] + brs[cb+j];
    }
    if (node < N){
      float4* po = (float4*)(out_s + (size_t)node*128 + cb);
      #pragma unroll
      for (int q = 0; q < 4; q++)
        po[q] = make_float4(o[4*q],o[4*q+1],o[4*q+2],o[4*q+3]);
    }
  }
  __syncthreads();   // gate ready

  // ---- vector GEMVs: fully register-resident per lane ----
  {
    const int vb = wv*6;                 // 8 waves x 6 = 48 channels
    float sv[48];
    float s3 = 0.f;
    if (node < N){
      const float4* pv = (const float4*)(node_v + (size_t)node*48);
      #pragma unroll
      for (int q = 0; q < 12; q++){
        const float4 v = pv[q];
        sv[4*q]=v.x; sv[4*q+1]=v.y; sv[4*q+2]=v.z; sv[4*q+3]=v.w;
        s3 += (v.x*v.x+v.y*v.y)+(v.z*v.z+v.w*v.w);
      }
    } else {
      #pragma unroll
      for (int k = 0; k < 48; k++) sv[k]=0.f;
    }
    const float rvn = rsqrtf(s3*(1.f/16.f) + 1e-8f);
    #pragma unroll
    for (int k = 0; k < 48; k++) sv[k] *= rvn;     // sv = vn

    float a1[6], a2[6];
    #pragma unroll
    for (int j = 0; j < 6; j++){ a1[j]=0.f; a2[j]=0.f; }

    #pragma unroll
    for (int kc = 0; kc < 48; kc += 8){
      float xv[8];
      if (node < N){
        const float4* pa = (const float4*)(aggV + (size_t)node*48 + kc);
        const float4 av0 = pa[0], av1 = pa[1];
        xv[0]=sv[kc]+av0.x;   xv[1]=sv[kc+1]+av0.y;
        xv[2]=sv[kc+2]+av0.z; xv[3]=sv[kc+3]+av0.w;
        xv[4]=sv[kc+4]+av1.x; xv[5]=sv[kc+5]+av1.y;
        xv[6]=sv[kc+6]+av1.z; xv[7]=sv[kc+7]+av1.w;
      } else {
        #pragma unroll
        for (int q = 0; q < 8; q++) xv[q] = 0.f;
      }
      #pragma unroll
      for (int j = 0; j < 6; j++){
        const float* w1 = wnv + (size_t)(vb+j)*48 + kc;
        const float* w2 = wrv + (size_t)(vb+j)*48 + kc;
        const float4 u0 = ((const float4*)w1)[0], u1 = ((const float4*)w1)[1];
        const float4 y0 = ((const float4*)w2)[0], y1 = ((const float4*)w2)[1];
        a1[j] += (xv[0]*u0.x + xv[1]*u0.y + xv[2]*u0.z + xv[3]*u0.w)
               + (xv[4]*u1.x + xv[5]*u1.y + xv[6]*u1.z + xv[7]*u1.w);
        a2[j] += (sv[kc]*y0.x + sv[kc+1]*y0.y + sv[kc+2]*y0.z + sv[kc+3]*y0.w)
               + (sv[kc+4]*y1.x + sv[kc+5]*y1.y + sv[kc+6]*y1.z + sv[kc+7]*y1.w);
      }
    }
    if (node < N){
      const float g0 = shGate[lane*NS_GS + 2*wv];
      const float g1 = shGate[lane*NS_GS + 2*wv + 1];
      float ov[6];
      #pragma unroll
      for (int j = 0; j < 6; j++){
        const float g = (j < 3) ? g0 : g1;
        ov[j] = (a1[j] + bnv[vb+j])*g + a2[j] + brv[vb+j];
      }
      float2* po = (float2*)(out_v + (size_t)node*48 + vb);
      po[0] = make_float2(ov[0], ov[1]);
      po[1] = make_float2(ov[2], ov[3]);
      po[2] = make_float2(ov[4], ov[5]);
    }
  }
}

extern "C" void kernel_launch(void* const* d_in, const int* in_sizes, int n_in,
                              void* d_out, int out_size, void* d_ws, size_t ws_size,
                              hipStream_t stream)
{
  const float* node_s = (const float*)d_in[0];
  const float* node_v = (const float*)d_in[1];
  const int*   eidx   = (const int*)  d_in[2];
  const float* edge_s = (const float*)d_in[3];
  const float* edge_v = (const float*)d_in[4];
  const float* ln_g   = (const float*)d_in[5];
  const float* ln_b   = (const float*)d_in[6];
  const float* wes    = (const float*)d_in[7];
  const float* bes    = (const float*)d_in[8];
  const float* wev    = (const float*)d_in[9];
  const float* bev    = (const float*)d_in[10];
  const float* wns    = (const float*)d_in[11];
  const float* bns    = (const float*)d_in[12];
  const float* wnv    = (const float*)d_in[13];
  const float* bnv    = (const float*)d_in[14];
  const float* wrs    = (const float*)d_in[15];
  const float* brs    = (const float*)d_in[16];
  const float* wrv    = (const float*)d_in[17];
  const float* brv    = (const float*)d_in[18];

  const int N = in_sizes[0] / 128;
  const int E = in_sizes[3] / 32;
  const int* dst = eidx + E;     // edge_index row 1

  // Workspace layout: [aggS N*128][aggV N*48][ecS E*128][ecV E*48]
  float* aggS = (float*)d_ws;
  float* aggV = aggS + (size_t)N*128;
  float* ecS  = aggS + (size_t)N*176;
  float* ecV  = ecS  + (size_t)E*128;
  const size_t need = ((size_t)N*176 + (size_t)E*176) * sizeof(float);

  // CSR scratch in the FRONT of d_out (3.6 MB); dead before node_kernel writes.
  int* off  = (int*)d_out;
  int* wptr = off + (N + 1);
  int* csr  = wptr + N;

  hipMemsetAsync(wptr, 0, (size_t)N*sizeof(int), stream);
  hist_kernel<<<(E+255)/256, 256, 0, stream>>>(dst, wptr, E);
  scan_kernel<<<1, 1024, 0, stream>>>(wptr, off, wptr, N);
  scatter_kernel<<<(E+255)/256, 256, 0, stream>>>(dst, wptr, csr, E);

  if (ws_size >= need){
    edge_gvp_kernel<<<(E+255)/256, 256, 0, stream>>>(edge_s, edge_v, csr,
                                                     wes, bes, wev, bev,
                                                     ecS, ecV, E);
    agg_kernel<<<(N+AGG_NB-1)/AGG_NB, 192, 0, stream>>>(ecS, ecV, off,
                                                        aggS, aggV, N);
  } else {
    edge_agg_kernel<<<N, 128, 0, stream>>>(edge_s, edge_v, csr, off,
                                           wes, bes, wev, bev, aggS, aggV, N);
  }

  float* out_s = (float*)d_out;
  float* out_v = out_s + (size_t)N*128;
  node_kernel<<<(N+63)/64, 512, 0, stream>>>(node_s, node_v, ln_g, ln_b,
                                             wns, bns, wnv, bnv,
                                             wrs, brs, wrv, brv,
                                             aggS, aggV, out_s, out_v, N);
}

// Round 6
// 777.795 us; speedup vs baseline: 1.0839x; 1.0839x over previous
//
#include <hip/hip_runtime.h>

__device__ __forceinline__ float sigmoidf_(float x){ return 1.f/(1.f+__expf(-x)); }

// ---------- CSR build ----------
__global__ void hist_kernel(const int* __restrict__ dst, int* __restrict__ cnt, int E){
  int e = blockIdx.x*blockDim.x + threadIdx.x;
  if (e < E) atomicAdd(&cnt[dst[e]], 1);
}

// cnt and wptr may ALIAS: cnt[i] read before wptr[i] written (same thread).
__global__ __launch_bounds__(1024) void scan_kernel(const int* __restrict__ cnt,
                                                    int* __restrict__ off,
                                                    int* __restrict__ wptr, int N){
  __shared__ int part[1024];
  const int t = threadIdx.x;
  const int chunk = (N + 1023) / 1024;
  const int lo = min(t*chunk, N), hi = min(lo+chunk, N);
  int s = 0;
  for (int i = lo; i < hi; i++) s += cnt[i];
  part[t] = s;
  __syncthreads();
  for (int o = 1; o < 1024; o <<= 1){
    int v = (t >= o) ? part[t-o] : 0;
    __syncthreads();
    part[t] += v;
    __syncthreads();
  }
  int run = part[t] - s;
  for (int i = lo; i < hi; i++){
    int c = cnt[i];
    off[i] = run; wptr[i] = run;
    run += c;
  }
  if (t == 1023) off[N] = part[1023];
}

// Also emit pos -> node map so the edge phase can do segmented reduction.
__global__ void scatter_kernel(const int* __restrict__ dst, int* __restrict__ wptr,
                               int* __restrict__ csr, int* __restrict__ node2, int E){
  int e = blockIdx.x*blockDim.x + threadIdx.x;
  if (e < E){
    int d = dst[e];
    int pos = atomicAdd(&wptr[d], 1);
    csr[pos] = e;
    node2[pos] = d;
  }
}

// ---------- Edge phase v7: edge-in-lanes, wave-uniform weights, LDS segmented mean ----------
// thread = CSR position. Per-thread state is small + static-indexed (es[32]),
// weights are wave-uniform (s_load from K$) — the codegen shape proven by
// node_kernel (VGPR 96, no junk). Runs of equal node are contiguous in CSR
// order; interior runs are COMPLETE nodes -> direct store of mean; block's
// first/last runs are partial -> atomicAdd(sum/deg). aggS/aggV pre-zeroed.
__global__ __launch_bounds__(256) void edge_agg2_kernel(
    const float* __restrict__ edge_s, const float* __restrict__ edge_v,
    const int* __restrict__ csr, const int* __restrict__ node2,
    const int* __restrict__ off,
    const float* __restrict__ wes, const float* __restrict__ bes,
    const float* __restrict__ wev, const float* __restrict__ bev,
    float* __restrict__ aggS, float* __restrict__ aggV, int E)
{
  __shared__ float shT[256*17];       // 256 positions x 16 ch (pad 17)
  __shared__ int   shNid[256];
  __shared__ int   shRunStart[258];   // +sentinel
  __shared__ int   shRunNode[257];
  __shared__ int   shWaveCnt[4];
  __shared__ int   shNumRuns, shActCnt;

  const int t  = threadIdx.x;
  const int wv = t >> 6, ln = t & 63;
  const int p0 = blockIdx.x * 256;
  const int p  = p0 + t;
  const bool act = (p < E);

  int e = 0, nid = -1;
  if (act){ e = csr[p]; nid = node2[p]; }

  // per-thread edge features (static-indexed registers)
  float es[32];
  float ev0 = 0.f, ev1 = 0.f, ev2 = 0.f;
  if (act){
    #pragma unroll
    for (int k = 0; k < 32; k += 4){
      float4 u = *(const float4*)(edge_s + (size_t)e*32 + k);
      es[k]=u.x; es[k+1]=u.y; es[k+2]=u.z; es[k+3]=u.w;
    }
    const float* pv = edge_v + (size_t)e*3;
    ev0 = pv[0]; ev1 = pv[1]; ev2 = pv[2];
  } else {
    #pragma unroll
    for (int k = 0; k < 32; k++) es[k] = 0.f;
  }

  // ---- run table: heads, starts, nodes (once per block) ----
  shNid[t] = nid;
  __syncthreads();
  const int prevN = (t == 0) ? -2 : shNid[t-1];
  const bool flag = act && (nid != prevN);
  const unsigned long long bal = __ballot(flag);
  if (ln == 0) shWaveCnt[wv] = __popcll(bal);
  __syncthreads();
  if (t == 0){
    int s = 0;
    #pragma unroll
    for (int k = 0; k < 4; k++){ int c = shWaveCnt[k]; shWaveCnt[k] = s; s += c; }
    shNumRuns = s;
    shActCnt  = min(E - p0, 256);
  }
  __syncthreads();
  const int numRuns = shNumRuns;
  if (flag){
    const int rid = shWaveCnt[wv] + __popcll(bal & ((1ull<<ln) - 1ull));
    shRunStart[rid] = t;
    shRunNode[rid]  = nid;
  }
  if (t == 0) shRunStart[numRuns] = shActCnt;
  __syncthreads();

  // reduction over runs: thread -> (run r, channel c); interior runs are
  // complete nodes (bounded by other runs on both sides).
#define REDUCE_STORE(BASE, STRIDE, CHBASE)                                    \
  for (int r = (t >> 4); r < numRuns; r += 16){                               \
    const int c  = t & 15;                                                    \
    const int s0 = shRunStart[r], s1 = shRunStart[r+1];                       \
    const int nd = shRunNode[r];                                              \
    float sum = 0.f;                                                          \
    for (int j = s0; j < s1; j++) sum += shT[j*17 + c];                       \
    if (r == 0 || r == numRuns-1){                                            \
      const int deg = off[nd+1] - off[nd];                                    \
      atomicAdd(BASE + (size_t)nd*STRIDE + (CHBASE) + c,                      \
                sum * (1.f/(float)deg));                                      \
    } else {                                                                  \
      BASE[(size_t)nd*STRIDE + (CHBASE) + c] = sum * (1.f/(float)(s1 - s0));  \
    }                                                                         \
  }

  // ---- scalar channels: 8 chunks of 16, wave-uniform weight rows ----
  float g16[16];                      // vector gates from channels 0..15
  for (int cb = 0; cb < 128; cb += 16){
    float acc[16];
    #pragma unroll
    for (int c = 0; c < 16; c++){
      float a = bes[cb+c];
      const float* wr = wes + (size_t)(cb+c)*32;
      #pragma unroll
      for (int k = 0; k < 32; k++) a += es[k]*wr[k];
      acc[c] = a * sigmoidf_(a);                     // silu
    }
    if (cb == 0){
      #pragma unroll
      for (int c = 0; c < 16; c++) g16[c] = sigmoidf_(acc[c]);
    }
    __syncthreads();                 // tile WAR vs previous chunk's reduce
    #pragma unroll
    for (int c = 0; c < 16; c += 4)
      *(float4*)&shT[t*17 + c] = make_float4(acc[c],acc[c+1],acc[c+2],acc[c+3]);
    __syncthreads();
    REDUCE_STORE(aggS, 128, cb)
  }

  // ---- vector channels: 3 chunks of 16 (unrolled: g16 index must be static) ----
  #pragma unroll
  for (int vb = 0; vb < 48; vb += 16){
    float vo[16];
    #pragma unroll
    for (int cc = 0; cc < 16; cc++){
      const int c = vb + cc;
      vo[cc] = (bev[c] + wev[c*3]*ev0 + wev[c*3+1]*ev1 + wev[c*3+2]*ev2)
               * g16[c/3];
    }
    __syncthreads();
    #pragma unroll
    for (int c = 0; c < 16; c += 4)
      *(float4*)&shT[t*17 + c] = make_float4(vo[c],vo[c+1],vo[c+2],vo[c+3]);
    __syncthreads();
    REDUCE_STORE(aggV, 48, vb)
  }
#undef REDUCE_STORE
}

// ---------- Node phase v3: 64-node tiles, full-wave-uniform (scalar) weights ----------
#define NS_RS 68
#define NS_GS 17

__global__ __launch_bounds__(512, 4) void node_kernel(
    const float* __restrict__ node_s, const float* __restrict__ node_v,
    const float* __restrict__ ln_g, const float* __restrict__ ln_b,
    const float* __restrict__ wns, const float* __restrict__ bns,
    const float* __restrict__ wnv, const float* __restrict__ bnv,
    const float* __restrict__ wrs, const float* __restrict__ brs,
    const float* __restrict__ wrv, const float* __restrict__ brv,
    const float* __restrict__ aggS, const float* __restrict__ aggV,
    float* __restrict__ out_s, float* __restrict__ out_v, int N)
{
  __shared__ float shX[64*NS_RS];        // inS = sn + aggS   (current k-half)
  __shared__ float shS[64*NS_RS];        // sn                (current k-half)
  __shared__ float shP1[128], shP2[128]; // LN partial sums (2 k-halves)
  __shared__ float shGate[64*NS_GS];

  const int tid  = threadIdx.x;
  const int lane = tid & 63;
  const int wv   = __builtin_amdgcn_readfirstlane(tid >> 6);   // 0..7, SGPR
  const int i0   = blockIdx.x * 64;
  const int node = i0 + lane;

  // ---- LN stats: waves 0,1 each sum one k-half, lane = node ----
  if (wv < 2){
    float s1 = 0.f, s2 = 0.f;
    if (node < N){
      const float4* p = (const float4*)(node_s + (size_t)node*128 + wv*64);
      #pragma unroll
      for (int q = 0; q < 16; q++){
        const float4 v = p[q];
        s1 += (v.x+v.y)+(v.z+v.w);
        s2 += (v.x*v.x+v.y*v.y)+(v.z*v.z+v.w*v.w);
      }
    }
    shP1[wv*64+lane] = s1;
    shP2[wv*64+lane] = s2;
  }
  __syncthreads();

  float acc1[16], acc2[16];
  #pragma unroll
  for (int j = 0; j < 16; j++){ acc1[j]=0.f; acc2[j]=0.f; }
  const int cb = wv*16;

  for (int half = 0; half < 2; half++){
    const int kb = half*64;
    // ---- stage 64 nodes x 64 k: normalized (+agg) ----
    {
      const int n  = tid >> 3;           // 0..63
      const int kk = (tid & 7)*8;        // 0..56
      const int gn = i0 + n;
      const float s1 = shP1[n] + shP1[64+n];
      const float s2 = shP2[n] + shP2[64+n];
      const float m  = s1 * (1.f/128.f);
      const float r  = rsqrtf(s2*(1.f/128.f) - m*m + 1e-5f);
      float4 x0 = make_float4(0.f,0.f,0.f,0.f), x1 = x0, a0 = x0, a1v = x0;
      if (gn < N){
        const float4* ps = (const float4*)(node_s + (size_t)gn*128 + kb + kk);
        x0 = ps[0]; x1 = ps[1];
        const float4* pa = (const float4*)(aggS + (size_t)gn*128 + kb + kk);
        a0 = pa[0]; a1v = pa[1];
      }
      const float4 g0 = *(const float4*)(ln_g + kb + kk);
      const float4 g1 = *(const float4*)(ln_g + kb + kk + 4);
      const float4 b0 = *(const float4*)(ln_b + kb + kk);
      const float4 b1 = *(const float4*)(ln_b + kb + kk + 4);
      const float sn0 = (x0.x-m)*r*g0.x + b0.x;
      const float sn1 = (x0.y-m)*r*g0.y + b0.y;
      const float sn2 = (x0.z-m)*r*g0.z + b0.z;
      const float sn3 = (x0.w-m)*r*g0.w + b0.w;
      const float sn4 = (x1.x-m)*r*g1.x + b1.x;
      const float sn5 = (x1.y-m)*r*g1.y + b1.y;
      const float sn6 = (x1.z-m)*r*g1.z + b1.z;
      const float sn7 = (x1.w-m)*r*g1.w + b1.w;
      float* pS = &shS[n*NS_RS + kk];
      float* pX = &shX[n*NS_RS + kk];
      ((float4*)pS)[0] = make_float4(sn0,sn1,sn2,sn3);
      ((float4*)pS)[1] = make_float4(sn4,sn5,sn6,sn7);
      ((float4*)pX)[0] = make_float4(sn0+a0.x, sn1+a0.y, sn2+a0.z, sn3+a0.w);
      ((float4*)pX)[1] = make_float4(sn4+a1v.x, sn5+a1v.y, sn6+a1v.z, sn7+a1v.w);
    }
    __syncthreads();

    // ---- scalar GEMVs: wave-uniform weight rows, lane = node ----
    for (int kc = 0; kc < 64; kc += 8){
      const float4 xa = ((const float4*)&shX[lane*NS_RS + kc])[0];
      const float4 xb = ((const float4*)&shX[lane*NS_RS + kc])[1];
      const float4 sa = ((const float4*)&shS[lane*NS_RS + kc])[0];
      const float4 sb = ((const float4*)&shS[lane*NS_RS + kc])[1];
      #pragma unroll
      for (int j = 0; j < 16; j++){
        const float* w1 = wns + (size_t)(cb+j)*128 + kb + kc;
        const float* w2 = wrs + (size_t)(cb+j)*128 + kb + kc;
        const float4 u0 = ((const float4*)w1)[0], u1 = ((const float4*)w1)[1];
        const float4 y0 = ((const float4*)w2)[0], y1 = ((const float4*)w2)[1];
        acc1[j] += (xa.x*u0.x + xa.y*u0.y + xa.z*u0.z + xa.w*u0.w)
                 + (xb.x*u1.x + xb.y*u1.y + xb.z*u1.z + xb.w*u1.w);
        acc2[j] += (sa.x*y0.x + sa.y*y0.y + sa.z*y0.z + sa.w*y0.w)
                 + (sb.x*y1.x + sb.y*y1.y + sb.z*y1.z + sb.w*y1.w);
      }
    }
    __syncthreads();   // before restage (half=1) / before gate write (exit)
  }

  // ---- scalar epilogue: silu + gate + residual, contiguous float4 stores ----
  {
    float o[16];
    #pragma unroll
    for (int j = 0; j < 16; j++){
      const float aa = acc1[j] + bns[cb+j];
      const float so = aa * sigmoidf_(aa);          // silu
      if (wv == 0) shGate[lane*NS_GS + j] = sigmoidf_(so);
      o[j] = so + acc2[j] + brs[cb+j];
    }
    if (node < N){
      float4* po = (float4*)(out_s + (size_t)node*128 + cb);
      #pragma unroll
      for (int q = 0; q < 4; q++)
        po[q] = make_float4(o[4*q],o[4*q+1],o[4*q+2],o[4*q+3]);
    }
  }
  __syncthreads();   // gate ready

  // ---- vector GEMVs: fully register-resident per lane ----
  {
    const int vb = wv*6;                 // 8 waves x 6 = 48 channels
    float sv[48];
    float s3 = 0.f;
    if (node < N){
      const float4* pv = (const float4*)(node_v + (size_t)node*48);
      #pragma unroll
      for (int q = 0; q < 12; q++){
        const float4 v = pv[q];
        sv[4*q]=v.x; sv[4*q+1]=v.y; sv[4*q+2]=v.z; sv[4*q+3]=v.w;
        s3 += (v.x*v.x+v.y*v.y)+(v.z*v.z+v.w*v.w);
      }
    } else {
      #pragma unroll
      for (int k = 0; k < 48; k++) sv[k]=0.f;
    }
    const float rvn = rsqrtf(s3*(1.f/16.f) + 1e-8f);
    #pragma unroll
    for (int k = 0; k < 48; k++) sv[k] *= rvn;     // sv = vn

    float a1[6], a2[6];
    #pragma unroll
    for (int j = 0; j < 6; j++){ a1[j]=0.f; a2[j]=0.f; }

    #pragma unroll
    for (int kc = 0; kc < 48; kc += 8){
      float xv[8];
      if (node < N){
        const float4* pa = (const float4*)(aggV + (size_t)node*48 + kc);
        const float4 av0 = pa[0], av1 = pa[1];
        xv[0]=sv[kc]+av0.x;   xv[1]=sv[kc+1]+av0.y;
        xv[2]=sv[kc+2]+av0.z; xv[3]=sv[kc+3]+av0.w;
        xv[4]=sv[kc+4]+av1.x; xv[5]=sv[kc+5]+av1.y;
        xv[6]=sv[kc+6]+av1.z; xv[7]=sv[kc+7]+av1.w;
      } else {
        #pragma unroll
        for (int q = 0; q < 8; q++) xv[q] = 0.f;
      }
      #pragma unroll
      for (int j = 0; j < 6; j++){
        const float* w1 = wnv + (size_t)(vb+j)*48 + kc;
        const float* w2 = wrv + (size_t)(vb+j)*48 + kc;
        const float4 u0 = ((const float4*)w1)[0], u1 = ((const float4*)w1)[1];
        const float4 y0 = ((const float4*)w2)[0], y1 = ((const float4*)w2)[1];
        a1[j] += (xv[0]*u0.x + xv[1]*u0.y + xv[2]*u0.z + xv[3]*u0.w)
               + (xv[4]*u1.x + xv[5]*u1.y + xv[6]*u1.z + xv[7]*u1.w);
        a2[j] += (sv[kc]*y0.x + sv[kc+1]*y0.y + sv[kc+2]*y0.z + sv[kc+3]*y0.w)
               + (sv[kc+4]*y1.x + sv[kc+5]*y1.y + sv[kc+6]*y1.z + sv[kc+7]*y1.w);
      }
    }
    if (node < N){
      const float g0 = shGate[lane*NS_GS + 2*wv];
      const float g1 = shGate[lane*NS_GS + 2*wv + 1];
      float ov[6];
      #pragma unroll
      for (int j = 0; j < 6; j++){
        const float g = (j < 3) ? g0 : g1;
        ov[j] = (a1[j] + bnv[vb+j])*g + a2[j] + brv[vb+j];
      }
      float2* po = (float2*)(out_v + (size_t)node*48 + vb);
      po[0] = make_float2(ov[0], ov[1]);
      po[1] = make_float2(ov[2], ov[3]);
      po[2] = make_float2(ov[4], ov[5]);
    }
  }
}

extern "C" void kernel_launch(void* const* d_in, const int* in_sizes, int n_in,
                              void* d_out, int out_size, void* d_ws, size_t ws_size,
                              hipStream_t stream)
{
  const float* node_s = (const float*)d_in[0];
  const float* node_v = (const float*)d_in[1];
  const int*   eidx   = (const int*)  d_in[2];
  const float* edge_s = (const float*)d_in[3];
  const float* edge_v = (const float*)d_in[4];
  const float* ln_g   = (const float*)d_in[5];
  const float* ln_b   = (const float*)d_in[6];
  const float* wes    = (const float*)d_in[7];
  const float* bes    = (const float*)d_in[8];
  const float* wev    = (const float*)d_in[9];
  const float* bev    = (const float*)d_in[10];
  const float* wns    = (const float*)d_in[11];
  const float* bns    = (const float*)d_in[12];
  const float* wnv    = (const float*)d_in[13];
  const float* bnv    = (const float*)d_in[14];
  const float* wrs    = (const float*)d_in[15];
  const float* brs    = (const float*)d_in[16];
  const float* wrv    = (const float*)d_in[17];
  const float* brv    = (const float*)d_in[18];

  const int N = in_sizes[0] / 128;
  const int E = in_sizes[3] / 32;
  const int* dst = eidx + E;     // edge_index row 1

  // agg arrays in d_ws: N*176*4 = 35.2 MB (proven-safe footprint).
  float* aggS = (float*)d_ws;
  float* aggV = aggS + (size_t)N*128;

  // CSR scratch in the FRONT of d_out (6.8 MB); dead before node_kernel writes.
  int* off   = (int*)d_out;
  int* wptr  = off + (N + 1);
  int* csr   = wptr + N;
  int* node2 = csr + E;

  hipMemsetAsync(wptr, 0, (size_t)N*sizeof(int), stream);
  hipMemsetAsync(aggS, 0, (size_t)N*176*sizeof(float), stream);  // boundary/deg-0 basis
  hist_kernel<<<(E+255)/256, 256, 0, stream>>>(dst, wptr, E);
  scan_kernel<<<1, 1024, 0, stream>>>(wptr, off, wptr, N);
  scatter_kernel<<<(E+255)/256, 256, 0, stream>>>(dst, wptr, csr, node2, E);

  edge_agg2_kernel<<<(E+255)/256, 256, 0, stream>>>(edge_s, edge_v, csr, node2, off,
                                                    wes, bes, wev, bev,
                                                    aggS, aggV, E);

  float* out_s = (float*)d_out;
  float* out_v = out_s + (size_t)N*128;
  node_kernel<<<(N+63)/64, 512, 0, stream>>>(node_s, node_v, ln_g, ln_b,
                                             wns, bns, wnv, bnv,
                                             wrs, brs, wrv, brv,
                                             aggS, aggV, out_s, out_v, N);
}

// Round 7
// 716.462 us; speedup vs baseline: 1.1767x; 1.0856x over previous
//
#include <hip/hip_runtime.h>

typedef __attribute__((ext_vector_type(8))) short short8v;
typedef __attribute__((ext_vector_type(4))) float f32x4;

__device__ __forceinline__ float sigmoidf_(float x){ return 1.f/(1.f+__expf(-x)); }

// split f32 -> bf16 hi + bf16 lo (truncation; residual captured by lo)
__device__ __forceinline__ void cvt8_hilo(const float* f, short8v& h, short8v& l){
  #pragma unroll
  for (int i = 0; i < 8; i++){
    const unsigned u = __builtin_bit_cast(unsigned, f[i]);
    h[i] = (short)(u >> 16);
    const float hf = __builtin_bit_cast(float, u & 0xFFFF0000u);
    const float lf = f[i] - hf;
    l[i] = (short)(__builtin_bit_cast(unsigned, lf) >> 16);
  }
}

// ---------- CSR build ----------
__global__ void hist_kernel(const int* __restrict__ dst, int* __restrict__ cnt, int E){
  int e = blockIdx.x*blockDim.x + threadIdx.x;
  if (e < E) atomicAdd(&cnt[dst[e]], 1);
}

// cnt and wptr may ALIAS: cnt[i] read before wptr[i] written (same thread).
__global__ __launch_bounds__(1024) void scan_kernel(const int* __restrict__ cnt,
                                                    int* __restrict__ off,
                                                    int* __restrict__ wptr, int N){
  __shared__ int part[1024];
  const int t = threadIdx.x;
  const int chunk = (N + 1023) / 1024;
  const int lo = min(t*chunk, N), hi = min(lo+chunk, N);
  int s = 0;
  for (int i = lo; i < hi; i++) s += cnt[i];
  part[t] = s;
  __syncthreads();
  for (int o = 1; o < 1024; o <<= 1){
    int v = (t >= o) ? part[t-o] : 0;
    __syncthreads();
    part[t] += v;
    __syncthreads();
  }
  int run = part[t] - s;
  for (int i = lo; i < hi; i++){
    int c = cnt[i];
    off[i] = run; wptr[i] = run;
    run += c;
  }
  if (t == 1023) off[N] = part[1023];
}

// Also emit pos -> node map so the edge phase can do segmented reduction.
__global__ void scatter_kernel(const int* __restrict__ dst, int* __restrict__ wptr,
                               int* __restrict__ csr, int* __restrict__ node2, int E){
  int e = blockIdx.x*blockDim.x + threadIdx.x;
  if (e < E){
    int d = dst[e];
    int pos = atomicAdd(&wptr[d], 1);
    csr[pos] = e;
    node2[pos] = d;
  }
}

// ---------- Edge phase v8: MFMA (bf16 hi/lo split) + LDS segmented mean ----------
// [256 edges x 32] @ [32 x 128] per block on the matrix cores. wes staged to
// LDS once as bf16 hi/lo (pad-40 rows). Wave w owns 64 edges (4 m-tiles of
// 16); per 16-channel chunk: 12 mfma (4 mt x 3 split products), bias+silu,
// then the v7-proven run-table segmented reduce. Fragment maps (gfx950
// 16x16x32): A lane(g,r)->A[r][8g+j]; B lane(g,c)->B[8g+j][c]; C row=(l>>4)*4+j,
// col=l&15 (learn_hip m89).
#define WES_PAD 40
__global__ __launch_bounds__(256, 3) void edge_agg3_kernel(
    const float* __restrict__ edge_s, const float* __restrict__ edge_v,
    const int* __restrict__ csr, const int* __restrict__ node2,
    const int* __restrict__ off,
    const float* __restrict__ wes, const float* __restrict__ bes,
    const float* __restrict__ wev, const float* __restrict__ bev,
    float* __restrict__ aggS, float* __restrict__ aggV, int E)
{
  __shared__ short wesH[128*WES_PAD];
  __shared__ short wesL[128*WES_PAD];
  __shared__ float shT[256*17];       // 256 positions x 16 ch (pad 17)
  __shared__ int   shE[256];
  __shared__ int   shNid[256];
  __shared__ int   shRunStart[258];   // +sentinel
  __shared__ int   shRunNode[257];
  __shared__ int   shWaveCnt[4];
  __shared__ int   shNumRuns, shActCnt;

  const int t  = threadIdx.x;
  const int wv = t >> 6, ln = t & 63;
  const int r15 = ln & 15, g4 = ln >> 4;
  const int p0 = blockIdx.x * 256;
  const int p  = p0 + t;
  const bool act = (p < E);

  // ---- stage wes -> LDS bf16 hi/lo: thread t covers 16 elems of one row ----
  {
    const int row = t >> 1, col = (t & 1)*16;
    const float* src = wes + row*32 + col;
    float f0[8], f1[8];
    #pragma unroll
    for (int q = 0; q < 8; q += 4){
      float4 u = *(const float4*)(src + q);
      f0[q]=u.x; f0[q+1]=u.y; f0[q+2]=u.z; f0[q+3]=u.w;
      float4 v = *(const float4*)(src + 8 + q);
      f1[q]=v.x; f1[q+1]=v.y; f1[q+2]=v.z; f1[q+3]=v.w;
    }
    short8v h0, l0, h1, l1;
    cvt8_hilo(f0, h0, l0);
    cvt8_hilo(f1, h1, l1);
    *(short8v*)&wesH[row*WES_PAD + col]     = h0;
    *(short8v*)&wesH[row*WES_PAD + col + 8] = h1;
    *(short8v*)&wesL[row*WES_PAD + col]     = l0;
    *(short8v*)&wesL[row*WES_PAD + col + 8] = l1;
  }

  // ---- edge ids, run table ----
  const int eSelf = csr[act ? p : (E-1)];
  int nid = -1;
  if (act) nid = node2[p];
  shE[t] = eSelf;
  shNid[t] = nid;
  __syncthreads();
  const int prevN = (t == 0) ? -2 : shNid[t-1];
  const bool flag = act && (nid != prevN);
  const unsigned long long bal = __ballot(flag);
  if (ln == 0) shWaveCnt[wv] = __popcll(bal);
  __syncthreads();
  if (t == 0){
    int s = 0;
    #pragma unroll
    for (int k = 0; k < 4; k++){ int c = shWaveCnt[k]; shWaveCnt[k] = s; s += c; }
    shNumRuns = s;
    shActCnt  = min(E - p0, 256);
  }
  __syncthreads();
  const int numRuns = shNumRuns;
  if (flag){
    const int rid = shWaveCnt[wv] + __popcll(bal & ((1ull<<ln) - 1ull));
    shRunStart[rid] = t;
    shRunNode[rid]  = nid;
  }
  if (t == 0) shRunStart[numRuns] = shActCnt;

  // ---- per-thread extras: ev (own edge), bias slice ----
  float ev0 = 0.f, ev1 = 0.f, ev2 = 0.f;
  if (act){
    const float* pv = edge_v + (size_t)eSelf*3;
    ev0 = pv[0]; ev1 = pv[1]; ev2 = pv[2];
  }
  float bs[8];
  #pragma unroll
  for (int cb = 0; cb < 8; cb++) bs[cb] = bes[cb*16 + r15];

  __syncthreads();   // shE + run table + wes LDS ready

  // ---- A fragments: 4 m-tiles, hi/lo ----
  short8v aH[4], aL[4];
  #pragma unroll
  for (int mt = 0; mt < 4; mt++){
    const int e_ = shE[wv*64 + mt*16 + r15];
    const float* pa = edge_s + (size_t)e_*32 + g4*8;
    float4 u0 = *(const float4*)pa, u1 = *(const float4*)(pa+4);
    float f[8] = {u0.x,u0.y,u0.z,u0.w,u1.x,u1.y,u1.z,u1.w};
    cvt8_hilo(f, aH[mt], aL[mt]);
  }

#define REDUCE_STORE(BASE, STRIDE, CHBASE)                                    \
  for (int r = (t >> 4); r < numRuns; r += 16){                               \
    const int c  = t & 15;                                                    \
    const int s0 = shRunStart[r], s1 = shRunStart[r+1];                       \
    const int nd = shRunNode[r];                                              \
    float sum = 0.f;                                                          \
    for (int j = s0; j < s1; j++) sum += shT[j*17 + c];                       \
    if (r == 0 || r == numRuns-1){                                            \
      const int deg = off[nd+1] - off[nd];                                    \
      atomicAdd(BASE + (size_t)nd*STRIDE + (CHBASE) + c,                      \
                sum * (1.f/(float)deg));                                      \
    } else {                                                                  \
      BASE[(size_t)nd*STRIDE + (CHBASE) + c] = sum * (1.f/(float)(s1 - s0));  \
    }                                                                         \
  }

  // ---- scalar channels: 8 chunks of 16 via MFMA ----
  float g16[16];
  for (int cb = 0; cb < 8; cb++){
    const int baddr = (cb*16 + r15)*WES_PAD + g4*8;
    const short8v bH = *(const short8v*)&wesH[baddr];
    const short8v bL = *(const short8v*)&wesL[baddr];
    f32x4 acc0 = {0.f,0.f,0.f,0.f}, acc1 = acc0, acc2 = acc0, acc3 = acc0;
    acc0 = __builtin_amdgcn_mfma_f32_16x16x32_bf16(aH[0], bH, acc0, 0,0,0);
    acc1 = __builtin_amdgcn_mfma_f32_16x16x32_bf16(aH[1], bH, acc1, 0,0,0);
    acc2 = __builtin_amdgcn_mfma_f32_16x16x32_bf16(aH[2], bH, acc2, 0,0,0);
    acc3 = __builtin_amdgcn_mfma_f32_16x16x32_bf16(aH[3], bH, acc3, 0,0,0);
    acc0 = __builtin_amdgcn_mfma_f32_16x16x32_bf16(aL[0], bH, acc0, 0,0,0);
    acc1 = __builtin_amdgcn_mfma_f32_16x16x32_bf16(aL[1], bH, acc1, 0,0,0);
    acc2 = __builtin_amdgcn_mfma_f32_16x16x32_bf16(aL[2], bH, acc2, 0,0,0);
    acc3 = __builtin_amdgcn_mfma_f32_16x16x32_bf16(aL[3], bH, acc3, 0,0,0);
    acc0 = __builtin_amdgcn_mfma_f32_16x16x32_bf16(aH[0], bL, acc0, 0,0,0);
    acc1 = __builtin_amdgcn_mfma_f32_16x16x32_bf16(aH[1], bL, acc1, 0,0,0);
    acc2 = __builtin_amdgcn_mfma_f32_16x16x32_bf16(aH[2], bL, acc2, 0,0,0);
    acc3 = __builtin_amdgcn_mfma_f32_16x16x32_bf16(aH[3], bL, acc3, 0,0,0);
    __syncthreads();   // WAR: previous chunk's reduce done with shT
    const float bb = bs[cb];
    #pragma unroll
    for (int j = 0; j < 4; j++){
      const int rbase = wv*64 + g4*4 + j;
      float a0 = acc0[j] + bb; shT[(rbase     )*17 + r15] = a0 * sigmoidf_(a0);
      float a1 = acc1[j] + bb; shT[(rbase + 16)*17 + r15] = a1 * sigmoidf_(a1);
      float a2 = acc2[j] + bb; shT[(rbase + 32)*17 + r15] = a2 * sigmoidf_(a2);
      float a3 = acc3[j] + bb; shT[(rbase + 48)*17 + r15] = a3 * sigmoidf_(a3);
    }
    __syncthreads();
    if (cb == 0){
      #pragma unroll
      for (int c = 0; c < 16; c++) g16[c] = sigmoidf_(shT[t*17 + c]);
    }
    REDUCE_STORE(aggS, 128, cb*16)
  }

  // ---- vector channels: 3 chunks of 16 (thread t = its own edge) ----
  #pragma unroll
  for (int vb = 0; vb < 48; vb += 16){
    float vo[16];
    #pragma unroll
    for (int cc = 0; cc < 16; cc++){
      const int c = vb + cc;
      vo[cc] = (bev[c] + wev[c*3]*ev0 + wev[c*3+1]*ev1 + wev[c*3+2]*ev2)
               * g16[c/3];
    }
    __syncthreads();
    #pragma unroll
    for (int c = 0; c < 16; c += 4)
      *(float4*)&shT[t*17 + c] = make_float4(vo[c],vo[c+1],vo[c+2],vo[c+3]);
    __syncthreads();
    REDUCE_STORE(aggV, 48, vb)
  }
#undef REDUCE_STORE
}

// ---------- Node phase v3: 64-node tiles, full-wave-uniform weights ----------
#define NS_RS 68
#define NS_GS 17

__global__ __launch_bounds__(512, 4) void node_kernel(
    const float* __restrict__ node_s, const float* __restrict__ node_v,
    const float* __restrict__ ln_g, const float* __restrict__ ln_b,
    const float* __restrict__ wns, const float* __restrict__ bns,
    const float* __restrict__ wnv, const float* __restrict__ bnv,
    const float* __restrict__ wrs, const float* __restrict__ brs,
    const float* __restrict__ wrv, const float* __restrict__ brv,
    const float* __restrict__ aggS, const float* __restrict__ aggV,
    float* __restrict__ out_s, float* __restrict__ out_v, int N)
{
  __shared__ float shX[64*NS_RS];        // inS = sn + aggS   (current k-half)
  __shared__ float shS[64*NS_RS];        // sn                (current k-half)
  __shared__ float shP1[128], shP2[128]; // LN partial sums (2 k-halves)
  __shared__ float shGate[64*NS_GS];

  const int tid  = threadIdx.x;
  const int lane = tid & 63;
  const int wv   = __builtin_amdgcn_readfirstlane(tid >> 6);   // 0..7, SGPR
  const int i0   = blockIdx.x * 64;
  const int node = i0 + lane;

  // ---- LN stats: waves 0,1 each sum one k-half, lane = node ----
  if (wv < 2){
    float s1 = 0.f, s2 = 0.f;
    if (node < N){
      const float4* p = (const float4*)(node_s + (size_t)node*128 + wv*64);
      #pragma unroll
      for (int q = 0; q < 16; q++){
        const float4 v = p[q];
        s1 += (v.x+v.y)+(v.z+v.w);
        s2 += (v.x*v.x+v.y*v.y)+(v.z*v.z+v.w*v.w);
      }
    }
    shP1[wv*64+lane] = s1;
    shP2[wv*64+lane] = s2;
  }
  __syncthreads();

  float acc1[16], acc2[16];
  #pragma unroll
  for (int j = 0; j < 16; j++){ acc1[j]=0.f; acc2[j]=0.f; }
  const int cb = wv*16;

  for (int half = 0; half < 2; half++){
    const int kb = half*64;
    // ---- stage 64 nodes x 64 k: normalized (+agg) ----
    {
      const int n  = tid >> 3;           // 0..63
      const int kk = (tid & 7)*8;        // 0..56
      const int gn = i0 + n;
      const float s1 = shP1[n] + shP1[64+n];
      const float s2 = shP2[n] + shP2[64+n];
      const float m  = s1 * (1.f/128.f);
      const float r  = rsqrtf(s2*(1.f/128.f) - m*m + 1e-5f);
      float4 x0 = make_float4(0.f,0.f,0.f,0.f), x1 = x0, a0 = x0, a1v = x0;
      if (gn < N){
        const float4* ps = (const float4*)(node_s + (size_t)gn*128 + kb + kk);
        x0 = ps[0]; x1 = ps[1];
        const float4* pa = (const float4*)(aggS + (size_t)gn*128 + kb + kk);
        a0 = pa[0]; a1v = pa[1];
      }
      const float4 g0 = *(const float4*)(ln_g + kb + kk);
      const float4 g1 = *(const float4*)(ln_g + kb + kk + 4);
      const float4 b0 = *(const float4*)(ln_b + kb + kk);
      const float4 b1 = *(const float4*)(ln_b + kb + kk + 4);
      const float sn0 = (x0.x-m)*r*g0.x + b0.x;
      const float sn1 = (x0.y-m)*r*g0.y + b0.y;
      const float sn2 = (x0.z-m)*r*g0.z + b0.z;
      const float sn3 = (x0.w-m)*r*g0.w + b0.w;
      const float sn4 = (x1.x-m)*r*g1.x + b1.x;
      const float sn5 = (x1.y-m)*r*g1.y + b1.y;
      const float sn6 = (x1.z-m)*r*g1.z + b1.z;
      const float sn7 = (x1.w-m)*r*g1.w + b1.w;
      float* pS = &shS[n*NS_RS + kk];
      float* pX = &shX[n*NS_RS + kk];
      ((float4*)pS)[0] = make_float4(sn0,sn1,sn2,sn3);
      ((float4*)pS)[1] = make_float4(sn4,sn5,sn6,sn7);
      ((float4*)pX)[0] = make_float4(sn0+a0.x, sn1+a0.y, sn2+a0.z, sn3+a0.w);
      ((float4*)pX)[1] = make_float4(sn4+a1v.x, sn5+a1v.y, sn6+a1v.z, sn7+a1v.w);
    }
    __syncthreads();

    // ---- scalar GEMVs: wave-uniform weight rows, lane = node ----
    for (int kc = 0; kc < 64; kc += 8){
      const float4 xa = ((const float4*)&shX[lane*NS_RS + kc])[0];
      const float4 xb = ((const float4*)&shX[lane*NS_RS + kc])[1];
      const float4 sa = ((const float4*)&shS[lane*NS_RS + kc])[0];
      const float4 sb = ((const float4*)&shS[lane*NS_RS + kc])[1];
      #pragma unroll
      for (int j = 0; j < 16; j++){
        const float* w1 = wns + (size_t)(cb+j)*128 + kb + kc;
        const float* w2 = wrs + (size_t)(cb+j)*128 + kb + kc;
        const float4 u0 = ((const float4*)w1)[0], u1 = ((const float4*)w1)[1];
        const float4 y0 = ((const float4*)w2)[0], y1 = ((const float4*)w2)[1];
        acc1[j] += (xa.x*u0.x + xa.y*u0.y + xa.z*u0.z + xa.w*u0.w)
                 + (xb.x*u1.x + xb.y*u1.y + xb.z*u1.z + xb.w*u1.w);
        acc2[j] += (sa.x*y0.x + sa.y*y0.y + sa.z*y0.z + sa.w*y0.w)
                 + (sb.x*y1.x + sb.y*y1.y + sb.z*y1.z + sb.w*y1.w);
      }
    }
    __syncthreads();   // before restage (half=1) / before gate write (exit)
  }

  // ---- scalar epilogue: silu + gate + residual, contiguous float4 stores ----
  {
    float o[16];
    #pragma unroll
    for (int j = 0; j < 16; j++){
      const float aa = acc1[j] + bns[cb+j];
      const float so = aa * sigmoidf_(aa);          // silu
      if (wv == 0) shGate[lane*NS_GS + j] = sigmoidf_(so);
      o[j] = so + acc2[j] + brs[cb+j];
    }
    if (node < N){
      float4* po = (float4*)(out_s + (size_t)node*128 + cb);
      #pragma unroll
      for (int q = 0; q < 4; q++)
        po[q] = make_float4(o[4*q],o[4*q+1],o[4*q+2],o[4*q+3]);
    }
  }
  __syncthreads();   // gate ready

  // ---- vector GEMVs: fully register-resident per lane ----
  {
    const int vb = wv*6;                 // 8 waves x 6 = 48 channels
    float sv[48];
    float s3 = 0.f;
    if (node < N){
      const float4* pv = (const float4*)(node_v + (size_t)node*48);
      #pragma unroll
      for (int q = 0; q < 12; q++){
        const float4 v = pv[q];
        sv[4*q]=v.x; sv[4*q+1]=v.y; sv[4*q+2]=v.z; sv[4*q+3]=v.w;
        s3 += (v.x*v.x+v.y*v.y)+(v.z*v.z+v.w*v.w);
      }
    } else {
      #pragma unroll
      for (int k = 0; k < 48; k++) sv[k]=0.f;
    }
    const float rvn = rsqrtf(s3*(1.f/16.f) + 1e-8f);
    #pragma unroll
    for (int k = 0; k < 48; k++) sv[k] *= rvn;     // sv = vn

    float a1[6], a2[6];
    #pragma unroll
    for (int j = 0; j < 6; j++){ a1[j]=0.f; a2[j]=0.f; }

    #pragma unroll
    for (int kc = 0; kc < 48; kc += 8){
      float xv[8];
      if (node < N){
        const float4* pa = (const float4*)(aggV + (size_t)node*48 + kc);
        const float4 av0 = pa[0], av1 = pa[1];
        xv[0]=sv[kc]+av0.x;   xv[1]=sv[kc+1]+av0.y;
        xv[2]=sv[kc+2]+av0.z; xv[3]=sv[kc+3]+av0.w;
        xv[4]=sv[kc+4]+av1.x; xv[5]=sv[kc+5]+av1.y;
        xv[6]=sv[kc+6]+av1.z; xv[7]=sv[kc+7]+av1.w;
      } else {
        #pragma unroll
        for (int q = 0; q < 8; q++) xv[q] = 0.f;
      }
      #pragma unroll
      for (int j = 0; j < 6; j++){
        const float* w1 = wnv + (size_t)(vb+j)*48 + kc;
        const float* w2 = wrv + (size_t)(vb+j)*48 + kc;
        const float4 u0 = ((const float4*)w1)[0], u1 = ((const float4*)w1)[1];
        const float4 y0 = ((const float4*)w2)[0], y1 = ((const float4*)w2)[1];
        a1[j] += (xv[0]*u0.x + xv[1]*u0.y + xv[2]*u0.z + xv[3]*u0.w)
               + (xv[4]*u1.x + xv[5]*u1.y + xv[6]*u1.z + xv[7]*u1.w);
        a2[j] += (sv[kc]*y0.x + sv[kc+1]*y0.y + sv[kc+2]*y0.z + sv[kc+3]*y0.w)
               + (sv[kc+4]*y1.x + sv[kc+5]*y1.y + sv[kc+6]*y1.z + sv[kc+7]*y1.w);
      }
    }
    if (node < N){
      const float g0 = shGate[lane*NS_GS + 2*wv];
      const float g1 = shGate[lane*NS_GS + 2*wv + 1];
      float ov[6];
      #pragma unroll
      for (int j = 0; j < 6; j++){
        const float g = (j < 3) ? g0 : g1;
        ov[j] = (a1[j] + bnv[vb+j])*g + a2[j] + brv[vb+j];
      }
      float2* po = (float2*)(out_v + (size_t)node*48 + vb);
      po[0] = make_float2(ov[0], ov[1]);
      po[1] = make_float2(ov[2], ov[3]);
      po[2] = make_float2(ov[4], ov[5]);
    }
  }
}

extern "C" void kernel_launch(void* const* d_in, const int* in_sizes, int n_in,
                              void* d_out, int out_size, void* d_ws, size_t ws_size,
                              hipStream_t stream)
{
  const float* node_s = (const float*)d_in[0];
  const float* node_v = (const float*)d_in[1];
  const int*   eidx   = (const int*)  d_in[2];
  const float* edge_s = (const float*)d_in[3];
  const float* edge_v = (const float*)d_in[4];
  const float* ln_g   = (const float*)d_in[5];
  const float* ln_b   = (const float*)d_in[6];
  const float* wes    = (const float*)d_in[7];
  const float* bes    = (const float*)d_in[8];
  const float* wev    = (const float*)d_in[9];
  const float* bev    = (const float*)d_in[10];
  const float* wns    = (const float*)d_in[11];
  const float* bns    = (const float*)d_in[12];
  const float* wnv    = (const float*)d_in[13];
  const float* bnv    = (const float*)d_in[14];
  const float* wrs    = (const float*)d_in[15];
  const float* brs    = (const float*)d_in[16];
  const float* wrv    = (const float*)d_in[17];
  const float* brv    = (const float*)d_in[18];

  const int N = in_sizes[0] / 128;
  const int E = in_sizes[3] / 32;
  const int* dst = eidx + E;     // edge_index row 1

  // agg arrays in d_ws: N*176*4 = 35.2 MB (proven-safe footprint).
  float* aggS = (float*)d_ws;
  float* aggV = aggS + (size_t)N*128;

  // CSR scratch in the FRONT of d_out (6.8 MB); dead before node_kernel writes.
  int* off   = (int*)d_out;
  int* wptr  = off + (N + 1);
  int* csr   = wptr + N;
  int* node2 = csr + E;

  hipMemsetAsync(wptr, 0, (size_t)N*sizeof(int), stream);
  hipMemsetAsync(aggS, 0, (size_t)N*176*sizeof(float), stream);  // boundary/deg-0 basis
  hist_kernel<<<(E+255)/256, 256, 0, stream>>>(dst, wptr, E);
  scan_kernel<<<1, 1024, 0, stream>>>(wptr, off, wptr, N);
  scatter_kernel<<<(E+255)/256, 256, 0, stream>>>(dst, wptr, csr, node2, E);

  edge_agg3_kernel<<<(E+255)/256, 256, 0, stream>>>(edge_s, edge_v, csr, node2, off,
                                                    wes, bes, wev, bev,
                                                    aggS, aggV, E);

  float* out_s = (float*)d_out;
  float* out_v = out_s + (size_t)N*128;
  node_kernel<<<(N+63)/64, 512, 0, stream>>>(node_s, node_v, ln_g, ln_b,
                                             wns, bns, wnv, bnv,
                                             wrs, brs, wrv, brv,
                                             aggS, aggV, out_s, out_v, N);
}